// Round 7
// baseline (48.187 us; speedup 1.0000x reference)
//
#include <hip/hip_runtime.h>
#include <math.h>

// PyramidROIAlign: B=2, N=1000, C=256, 7x7 pool, levels P2..P5 (256/128/64/32).
// K1: single-block counting sort of boxes by pyramid level -> order[].
// K2: per-pixel PixRec (level, 4 corner offsets, lx, ly), box-major.
// K3: gather+lerp in level-sorted box order (level-phased execution: the
//     whole GPU works on one level's map at a time -> L2-resident reads for
//     P5/P4 phases). Natural block order (round-robin XCD) for balance.

#define POOLN 7
#define CCH 256

typedef float f32x4 __attribute__((ext_vector_type(4)));

struct __align__(16) PixRec {
    int   tl, tr, bl, br;   // element offsets into the selected level map
    float lx, ly;
    int   li, pad;
};

// ---------------- K1: level counting sort (one block) ----------------
__global__ __launch_bounds__(1024) void roi_sort_kernel(
    const float* __restrict__ boxes,
    const float* __restrict__ meta,
    int* __restrict__ order,      // [n_boxes] box ids, level-sorted
    int* __restrict__ li_box,     // [n_boxes] scratch
    int* __restrict__ rank_box,   // [n_boxes] scratch
    int n_boxes)
{
    __shared__ int scnt[4];
    __shared__ int sbase[4];
    int tid = threadIdx.x;
    if (tid < 4) scnt[tid] = 0;
    __syncthreads();

    float area  = meta[4] * meta[5];
    float scale = 224.0f / sqrtf(area);

    for (int b = tid; b < n_boxes; b += blockDim.x) {
        float by1 = boxes[4*b+0], bx1 = boxes[4*b+1];
        float by2 = boxes[4*b+2], bx2 = boxes[4*b+3];
        float h = by2 - by1, w = bx2 - bx1;
        float rl = log2f(sqrtf(h * w) / scale);
        int lvl = 4 + (int)rintf(rl);
        lvl = lvl < 2 ? 2 : (lvl > 5 ? 5 : lvl);
        int li = lvl - 2;
        li_box[b]   = li;
        rank_box[b] = atomicAdd(&scnt[li], 1);
    }
    __syncthreads();
    if (tid == 0) {
        int acc = 0;
        for (int i = 0; i < 4; ++i) { sbase[i] = acc; acc += scnt[i]; }
    }
    __syncthreads();
    for (int b = tid; b < n_boxes; b += blockDim.x) {
        order[sbase[li_box[b]] + rank_box[b]] = b;
    }
}

// ---------------- K2: per-pixel record (box-major) ----------------
__global__ __launch_bounds__(256) void roi_prep_kernel(
    const float* __restrict__ boxes,
    const float* __restrict__ meta,
    PixRec* __restrict__ recs,
    int n_boxes, int boxes_per_batch)
{
    int t = blockIdx.x * blockDim.x + threadIdx.x;
    int total = n_boxes * 49;
    if (t >= total) return;

    int box = t / 49;
    int p   = t - box * 49;
    int py  = (p * 37) >> 8;            // p/7 for p in [0,49)
    int px  = p - py * 7;

    float by1 = boxes[4 * box + 0];
    float bx1 = boxes[4 * box + 1];
    float by2 = boxes[4 * box + 2];
    float bx2 = boxes[4 * box + 3];
    float h = by2 - by1, w = bx2 - bx1;

    // level: clip(4 + round_half_even(log2(sqrt(hw)/(224/sqrt(area)))), 2, 5)
    float area  = meta[4] * meta[5];
    float scale = 224.0f / sqrtf(area);
    float rl    = log2f(sqrtf(h * w) / scale);
    int lvl = 4 + (int)rintf(rl);
    lvl = lvl < 2 ? 2 : (lvl > 5 ? 5 : lvl);
    int li = lvl - 2;
    int H  = 256 >> li;
    float hm1 = (float)(H - 1);
    int b = box / boxes_per_batch;

    // y axis (reference arithmetic order)
    float gy  = (float)py / 6.0f;
    float ys  = (by1 + h * gy) * hm1;
    float fy0 = fminf(fmaxf(floorf(ys), 0.0f), hm1);
    int y0  = (int)fy0;
    int y1i = min(y0 + 1, H - 1);

    // x axis
    float gx  = (float)px / 6.0f;
    float xs  = (bx1 + w * gx) * hm1;
    float fx0 = fminf(fmaxf(floorf(xs), 0.0f), hm1);
    int x0  = (int)fx0;
    int x1i = min(x0 + 1, H - 1);

    int row0 = (b * H + y0)  * H;
    int row1 = (b * H + y1i) * H;

    PixRec r;
    r.tl = (row0 + x0)  * CCH;
    r.tr = (row0 + x1i) * CCH;
    r.bl = (row1 + x0)  * CCH;
    r.br = (row1 + x1i) * CCH;
    r.lx = xs - fx0;
    r.ly = ys - fy0;
    r.li = li;
    r.pad = 0;
    recs[t] = r;
}

// ---------------- K3: gather + bilinear lerp, level-sorted order ----------------
__device__ __forceinline__ f32x4 bilerp4(f32x4 tl, f32x4 tr, f32x4 bl, f32x4 br,
                                         float lx, float ly)
{
    f32x4 r;
    float top, bot;
    top = tl.x + (tr.x - tl.x) * lx; bot = bl.x + (br.x - bl.x) * lx; r.x = top + (bot - top) * ly;
    top = tl.y + (tr.y - tl.y) * lx; bot = bl.y + (br.y - bl.y) * lx; r.y = top + (bot - top) * ly;
    top = tl.z + (tr.z - tl.z) * lx; bot = bl.z + (br.z - bl.z) * lx; r.z = top + (bot - top) * ly;
    top = tl.w + (tr.w - tl.w) * lx; bot = bl.w + (br.w - bl.w) * lx; r.w = top + (bot - top) * ly;
    return r;
}

__global__ __launch_bounds__(256) void roi_gather_kernel(
    const int* __restrict__ order,
    const PixRec* __restrict__ recs,
    const float* __restrict__ f2,
    const float* __restrict__ f3,
    const float* __restrict__ f4,
    const float* __restrict__ f5,
    float* __restrict__ out,
    long total)
{
    long wid = (long)blockIdx.x * 256 + threadIdx.x;
    if (wid >= total) return;

    int  c4   = (int)(wid & 31);       // slot pair: co = c4*4 and co+128
    long t    = wid >> 5;              // sorted (box,pixel)
    int  sbox = (int)(t / 49);
    int  p    = (int)(t - (long)sbox * 49);

    int box = order[sbox];             // broadcast load (same for 1568 threads)
    long bp = (long)box * 49 + p;

    PixRec rec = recs[bp];             // one 32B broadcast load
    const float* f = (rec.li == 0) ? f2 : (rec.li == 1) ? f3 : (rec.li == 2) ? f4 : f5;
    float lx = rec.lx, ly = rec.ly;

    int co = c4 * 4;
    const float* ptl = f + rec.tl + co;
    const float* ptr2= f + rec.tr + co;
    const float* pbl = f + rec.bl + co;
    const float* pbr = f + rec.br + co;

    // 8 independent loads; each instruction = contiguous 512B per 32-lane group
    f32x4 tlA = *(const f32x4*)ptl;
    f32x4 trA = *(const f32x4*)ptr2;
    f32x4 blA = *(const f32x4*)pbl;
    f32x4 brA = *(const f32x4*)pbr;
    f32x4 tlB = *(const f32x4*)(ptl + 128);
    f32x4 trB = *(const f32x4*)(ptr2 + 128);
    f32x4 blB = *(const f32x4*)(pbl + 128);
    f32x4 brB = *(const f32x4*)(pbr + 128);

    f32x4 rA = bilerp4(tlA, trA, blA, brA, lx, ly);
    f32x4 rB = bilerp4(tlB, trB, blB, brB, lx, ly);

    long obase = bp * CCH + co;
    __builtin_nontemporal_store(rA, (f32x4*)(out + obase));
    __builtin_nontemporal_store(rB, (f32x4*)(out + obase + 128));
}

// ---------------- fallback: single kernel (round-1) ----------------
__global__ __launch_bounds__(256) void roi_align_kernel(
    const float* __restrict__ boxes,
    const float* __restrict__ meta,
    const float* __restrict__ f2,
    const float* __restrict__ f3,
    const float* __restrict__ f4,
    const float* __restrict__ f5,
    float* __restrict__ out,
    int boxes_per_batch,
    long total4)
{
    long idx = (long)blockIdx.x * blockDim.x + threadIdx.x;
    if (idx >= total4) return;

    int c4  = (int)(idx & 63);
    long t  = idx >> 6;
    int p   = (int)(t % 49);
    int box = (int)(t / 49);
    int py = p / 7, px = p % 7;

    float by1 = boxes[4 * box + 0];
    float bx1 = boxes[4 * box + 1];
    float by2 = boxes[4 * box + 2];
    float bx2 = boxes[4 * box + 3];

    float h = by2 - by1, w = bx2 - bx1;
    float area  = meta[4] * meta[5];
    float scale = 224.0f / sqrtf(area);
    float rl    = log2f(sqrtf(h * w) / scale);
    int lvl = 4 + (int)rintf(rl);
    lvl = lvl < 2 ? 2 : (lvl > 5 ? 5 : lvl);
    int li = lvl - 2;
    const float* f = (li == 0) ? f2 : (li == 1) ? f3 : (li == 2) ? f4 : f5;
    int H = 256 >> li;

    int b = box / boxes_per_batch;

    float gy = (float)py / 6.0f;
    float gx = (float)px / 6.0f;
    float ys = (by1 + (by2 - by1) * gy) * (float)(H - 1);
    float xs = (bx1 + (bx2 - bx1) * gx) * (float)(H - 1);

    float fy0 = fminf(fmaxf(floorf(ys), 0.0f), (float)(H - 1));
    float fx0 = fminf(fmaxf(floorf(xs), 0.0f), (float)(H - 1));
    int y0 = (int)fy0, x0 = (int)fx0;
    int y1i = min(y0 + 1, H - 1);
    int x1i = min(x0 + 1, H - 1);
    float ly = ys - fy0;
    float lx = xs - fx0;

    size_t row0 = ((size_t)b * H + y0)  * H;
    size_t row1 = ((size_t)b * H + y1i) * H;
    const f32x4* tl = (const f32x4*)(f + (row0 + x0)  * CCH) + c4;
    const f32x4* tr = (const f32x4*)(f + (row0 + x1i) * CCH) + c4;
    const f32x4* bl = (const f32x4*)(f + (row1 + x0)  * CCH) + c4;
    const f32x4* br = (const f32x4*)(f + (row1 + x1i) * CCH) + c4;

    f32x4 rr = bilerp4(*tl, *tr, *bl, *br, lx, ly);
    ((f32x4*)out)[idx] = rr;
}

extern "C" void kernel_launch(void* const* d_in, const int* in_sizes, int n_in,
                              void* d_out, int out_size, void* d_ws, size_t ws_size,
                              hipStream_t stream) {
    const float* boxes = (const float*)d_in[0];
    const float* meta  = (const float*)d_in[1];
    const float* f2    = (const float*)d_in[2];
    const float* f3    = (const float*)d_in[3];
    const float* f4    = (const float*)d_in[4];
    const float* f5    = (const float*)d_in[5];
    float* out         = (float*)d_out;

    int n_boxes = in_sizes[0] / 4;                       // B*N = 2000
    int B       = in_sizes[2] / (256 * 256 * 256);       // batch from feat_p2
    int boxes_per_batch = n_boxes / B;                   // N

    int    n_pix     = n_boxes * 49;
    size_t rec_bytes = (size_t)n_pix * sizeof(PixRec);
    size_t int_bytes = (size_t)n_boxes * sizeof(int);
    size_t need      = rec_bytes + 3 * int_bytes + 256;

    if (d_ws != nullptr && ws_size >= need) {
        PixRec* recs     = (PixRec*)d_ws;
        int*    order    = (int*)((char*)d_ws + rec_bytes);
        int*    li_box   = order + n_boxes;
        int*    rank_box = li_box + n_boxes;

        roi_sort_kernel<<<1, 1024, 0, stream>>>(
            boxes, meta, order, li_box, rank_box, n_boxes);

        roi_prep_kernel<<<(n_pix + 255) / 256, 256, 0, stream>>>(
            boxes, meta, recs, n_boxes, boxes_per_batch);

        long total = (long)n_pix * 32;                   // threads (8 floats each)
        int  nwg   = (int)((total + 255) / 256);
        roi_gather_kernel<<<nwg, 256, 0, stream>>>(
            order, recs, f2, f3, f4, f5, out, total);
    } else {
        long total4 = (long)n_boxes * 49 * 64;
        int  blocks = (int)((total4 + 255) / 256);
        roi_align_kernel<<<blocks, 256, 0, stream>>>(
            boxes, meta, f2, f3, f4, f5, out, boxes_per_batch, total4);
    }
}

// Round 8
// 42.375 us; speedup vs baseline: 1.1372x; 1.1372x over previous
//
#include <hip/hip_runtime.h>
#include <math.h>

// PyramidROIAlign: B=2, N=1000, C=256, 7x7 pool, levels P2..P5 (256/128/64/32).
// FINAL (best-measured) variant = round-6 structure:
//   Phase 1: one thread per output pixel resolves level + 4 absolute corner
//            offsets + lx/ly into one 32B PixRec (single dependent hop).
//   Phase 2: 8 floats/thread, c4 in [0,32), slots co=c4*4 and co+128
//            (contiguous 512B per 32-lane half-wave), NT stores, XCD swizzle.
// Measured 42.8 us; memory-system bound: 98MB write + ~72MB scattered read
// per replay at ~4.3 TB/s mixed = practical ceiling for this access pattern.

#define POOLN 7
#define CCH 256

typedef float f32x4 __attribute__((ext_vector_type(4)));

struct __align__(16) PixRec {
    int   tl, tr, bl, br;   // element offsets into the selected level map
    float lx, ly;
    int   li, pad;
};

// ---------------- phase 1: per-pixel record ----------------
__global__ __launch_bounds__(256) void roi_prep_kernel(
    const float* __restrict__ boxes,
    const float* __restrict__ meta,
    PixRec* __restrict__ recs,
    int n_boxes, int boxes_per_batch)
{
    int t = blockIdx.x * blockDim.x + threadIdx.x;
    int total = n_boxes * 49;
    if (t >= total) return;

    int box = t / 49;
    int p   = t - box * 49;
    int py  = (p * 37) >> 8;            // p/7 for p in [0,49)
    int px  = p - py * 7;

    float by1 = boxes[4 * box + 0];
    float bx1 = boxes[4 * box + 1];
    float by2 = boxes[4 * box + 2];
    float bx2 = boxes[4 * box + 3];
    float h = by2 - by1, w = bx2 - bx1;

    // level: clip(4 + round_half_even(log2(sqrt(hw)/(224/sqrt(area)))), 2, 5)
    float area  = meta[4] * meta[5];
    float scale = 224.0f / sqrtf(area);
    float rl    = log2f(sqrtf(h * w) / scale);
    int lvl = 4 + (int)rintf(rl);
    lvl = lvl < 2 ? 2 : (lvl > 5 ? 5 : lvl);
    int li = lvl - 2;
    int H  = 256 >> li;
    float hm1 = (float)(H - 1);
    int b = box / boxes_per_batch;

    // y axis (reference arithmetic order)
    float gy  = (float)py / 6.0f;
    float ys  = (by1 + h * gy) * hm1;
    float fy0 = fminf(fmaxf(floorf(ys), 0.0f), hm1);
    int y0  = (int)fy0;
    int y1i = min(y0 + 1, H - 1);

    // x axis
    float gx  = (float)px / 6.0f;
    float xs  = (bx1 + w * gx) * hm1;
    float fx0 = fminf(fmaxf(floorf(xs), 0.0f), hm1);
    int x0  = (int)fx0;
    int x1i = min(x0 + 1, H - 1);

    int row0 = (b * H + y0)  * H;
    int row1 = (b * H + y1i) * H;

    PixRec r;
    r.tl = (row0 + x0)  * CCH;
    r.tr = (row0 + x1i) * CCH;
    r.bl = (row1 + x0)  * CCH;
    r.br = (row1 + x1i) * CCH;
    r.lx = xs - fx0;
    r.ly = ys - fy0;
    r.li = li;
    r.pad = 0;
    recs[t] = r;
}

// ---------------- phase 2: gather + bilinear lerp ----------------
__device__ __forceinline__ f32x4 bilerp4(f32x4 tl, f32x4 tr, f32x4 bl, f32x4 br,
                                         float lx, float ly)
{
    f32x4 r;
    float top, bot;
    top = tl.x + (tr.x - tl.x) * lx; bot = bl.x + (br.x - bl.x) * lx; r.x = top + (bot - top) * ly;
    top = tl.y + (tr.y - tl.y) * lx; bot = bl.y + (br.y - bl.y) * lx; r.y = top + (bot - top) * ly;
    top = tl.z + (tr.z - tl.z) * lx; bot = bl.z + (br.z - bl.z) * lx; r.z = top + (bot - top) * ly;
    top = tl.w + (tr.w - tl.w) * lx; bot = bl.w + (br.w - bl.w) * lx; r.w = top + (bot - top) * ly;
    return r;
}

__global__ __launch_bounds__(256) void roi_gather_kernel(
    const PixRec* __restrict__ recs,
    const float* __restrict__ f2,
    const float* __restrict__ f3,
    const float* __restrict__ f4,
    const float* __restrict__ f5,
    float* __restrict__ out,
    int q, int r, long total)
{
    // bijective XCD-chunked swizzle (nwg = 8q + r)
    int bid    = blockIdx.x;
    int xcd    = bid & 7;
    int within = bid >> 3;
    int wg = (xcd < r ? xcd * (q + 1) : r * (q + 1) + (xcd - r) * q) + within;

    long wid = (long)wg * 256 + threadIdx.x;
    if (wid >= total) return;

    int  c4  = (int)(wid & 31);        // slot pair: co = c4*4 and co+128
    long t   = wid >> 5;               // (box,pixel)

    PixRec rec = recs[t];              // ONE 32B broadcast load (single hop)
    const float* f = (rec.li == 0) ? f2 : (rec.li == 1) ? f3 : (rec.li == 2) ? f4 : f5;
    float lx = rec.lx, ly = rec.ly;

    int co = c4 * 4;
    const float* ptl = f + rec.tl + co;
    const float* ptr2= f + rec.tr + co;
    const float* pbl = f + rec.bl + co;
    const float* pbr = f + rec.br + co;

    // 8 independent loads; each instruction = contiguous 512B per 32-lane group
    f32x4 tlA = *(const f32x4*)ptl;
    f32x4 trA = *(const f32x4*)ptr2;
    f32x4 blA = *(const f32x4*)pbl;
    f32x4 brA = *(const f32x4*)pbr;
    f32x4 tlB = *(const f32x4*)(ptl + 128);
    f32x4 trB = *(const f32x4*)(ptr2 + 128);
    f32x4 blB = *(const f32x4*)(pbl + 128);
    f32x4 brB = *(const f32x4*)(pbr + 128);

    f32x4 rA = bilerp4(tlA, trA, blA, brA, lx, ly);
    f32x4 rB = bilerp4(tlB, trB, blB, brB, lx, ly);

    long obase = t * CCH + co;
    __builtin_nontemporal_store(rA, (f32x4*)(out + obase));
    __builtin_nontemporal_store(rB, (f32x4*)(out + obase + 128));
}

// ---------------- fallback: single kernel (round-1) ----------------
__global__ __launch_bounds__(256) void roi_align_kernel(
    const float* __restrict__ boxes,
    const float* __restrict__ meta,
    const float* __restrict__ f2,
    const float* __restrict__ f3,
    const float* __restrict__ f4,
    const float* __restrict__ f5,
    float* __restrict__ out,
    int boxes_per_batch,
    long total4)
{
    long idx = (long)blockIdx.x * blockDim.x + threadIdx.x;
    if (idx >= total4) return;

    int c4  = (int)(idx & 63);
    long t  = idx >> 6;
    int p   = (int)(t % 49);
    int box = (int)(t / 49);
    int py = p / 7, px = p % 7;

    float by1 = boxes[4 * box + 0];
    float bx1 = boxes[4 * box + 1];
    float by2 = boxes[4 * box + 2];
    float bx2 = boxes[4 * box + 3];

    float h = by2 - by1, w = bx2 - bx1;
    float area  = meta[4] * meta[5];
    float scale = 224.0f / sqrtf(area);
    float rl    = log2f(sqrtf(h * w) / scale);
    int lvl = 4 + (int)rintf(rl);
    lvl = lvl < 2 ? 2 : (lvl > 5 ? 5 : lvl);
    int li = lvl - 2;
    const float* f = (li == 0) ? f2 : (li == 1) ? f3 : (li == 2) ? f4 : f5;
    int H = 256 >> li;

    int b = box / boxes_per_batch;

    float gy = (float)py / 6.0f;
    float gx = (float)px / 6.0f;
    float ys = (by1 + (by2 - by1) * gy) * (float)(H - 1);
    float xs = (bx1 + (bx2 - bx1) * gx) * (float)(H - 1);

    float fy0 = fminf(fmaxf(floorf(ys), 0.0f), (float)(H - 1));
    float fx0 = fminf(fmaxf(floorf(xs), 0.0f), (float)(H - 1));
    int y0 = (int)fy0, x0 = (int)fx0;
    int y1i = min(y0 + 1, H - 1);
    int x1i = min(x0 + 1, H - 1);
    float ly = ys - fy0;
    float lx = xs - fx0;

    size_t row0 = ((size_t)b * H + y0)  * H;
    size_t row1 = ((size_t)b * H + y1i) * H;
    const f32x4* tl = (const f32x4*)(f + (row0 + x0)  * CCH) + c4;
    const f32x4* tr = (const f32x4*)(f + (row0 + x1i) * CCH) + c4;
    const f32x4* bl = (const f32x4*)(f + (row1 + x0)  * CCH) + c4;
    const f32x4* br = (const f32x4*)(f + (row1 + x1i) * CCH) + c4;

    f32x4 rr = bilerp4(*tl, *tr, *bl, *br, lx, ly);
    ((f32x4*)out)[idx] = rr;
}

extern "C" void kernel_launch(void* const* d_in, const int* in_sizes, int n_in,
                              void* d_out, int out_size, void* d_ws, size_t ws_size,
                              hipStream_t stream) {
    const float* boxes = (const float*)d_in[0];
    const float* meta  = (const float*)d_in[1];
    const float* f2    = (const float*)d_in[2];
    const float* f3    = (const float*)d_in[3];
    const float* f4    = (const float*)d_in[4];
    const float* f5    = (const float*)d_in[5];
    float* out         = (float*)d_out;

    int n_boxes = in_sizes[0] / 4;                       // B*N = 2000
    int B       = in_sizes[2] / (256 * 256 * 256);       // batch from feat_p2
    int boxes_per_batch = n_boxes / B;                   // N

    int    n_pix = n_boxes * 49;
    size_t need  = (size_t)n_pix * sizeof(PixRec);

    if (d_ws != nullptr && ws_size >= need) {
        PixRec* recs = (PixRec*)d_ws;

        roi_prep_kernel<<<(n_pix + 255) / 256, 256, 0, stream>>>(
            boxes, meta, recs, n_boxes, boxes_per_batch);

        long total = (long)n_pix * 32;                   // threads (8 floats each)
        int  nwg   = (int)((total + 255) / 256);
        int  q = nwg >> 3, r = nwg & 7;
        roi_gather_kernel<<<nwg, 256, 0, stream>>>(
            recs, f2, f3, f4, f5, out, q, r, total);
    } else {
        long total4 = (long)n_boxes * 49 * 64;
        int  blocks = (int)((total4 + 255) / 256);
        roi_align_kernel<<<blocks, 256, 0, stream>>>(
            boxes, meta, f2, f3, f4, f5, out, boxes_per_batch, total4);
    }
}